// Round 3
// baseline (460.499 us; speedup 1.0000x reference)
//
#include <hip/hip_runtime.h>
#include <cstdint>
#include <cstddef>

// Problem: a[B=4,S=2048,K=4096] int8, w[K=4096,N=4096] int8,
// a_s[8192] f32 per-token scale, w_s[4096] f32 per-col scale.
// out[m][n] = fp16( (int32 dot) * a_s[m] * w_s[n] ), stored as f32 in d_out.
//
// HARNESS NOTE: integer inputs arrive as *int32* buffers (one int32 per
// reference int8 element). A fused pre-pass narrows them to packed int8 in
// d_ws (A: same layout; W: transposed to [N][K]) before the MFMA GEMM.

#define M_DIM 8192
#define N_DIM 4096
#define K_DIM 4096

// pack-A portion: one thread per 4 int32 -> 1 uint32. M*K/4 = 8M threads.
#define PACKA_BLOCKS ((M_DIM * K_DIM / 4) / 256)   // 32768
// transpose portion: 64x64 tiles -> (4096/64)*(4096/64) = 4096 blocks.
#define TRANS_BLOCKS ((N_DIM / 64) * (K_DIM / 64)) // 4096

typedef int v4i  __attribute__((ext_vector_type(4)));
typedef int v16i __attribute__((ext_vector_type(16)));

__device__ __forceinline__ uint32_t pack4(int x, int y, int z, int w)
{
    return (uint32_t)(x & 0xff) | ((uint32_t)(y & 0xff) << 8) |
           ((uint32_t)(z & 0xff) << 16) | ((uint32_t)(w & 0xff) << 24);
}

// ---------------------------------------------------------------------------
// Fused pre-pass — byte-identical to round 0/2 (attribution: GEMM-only change).
// ---------------------------------------------------------------------------
__global__ void __launch_bounds__(256) prepare_kernel(
    const int* __restrict__ a, const int* __restrict__ w,
    uint8_t* __restrict__ pa, uint8_t* __restrict__ wt)
{
    __shared__ int lds[64][65];        // used by transpose branch only

    if (blockIdx.x < PACKA_BLOCKS) {
        const size_t idx = (size_t)blockIdx.x * 256 + threadIdx.x;
        int4 x = ((const int4*)a)[idx];
        ((uint32_t*)pa)[idx] = pack4(x.x, x.y, x.z, x.w);
        return;
    }

    const int tile = blockIdx.x - PACKA_BLOCKS;
    const int t  = threadIdx.x;
    const int n0 = (tile & 63) * 64;
    const int k0 = (tile >> 6) * 64;

#pragma unroll
    for (int i = 0; i < 4; ++i) {
        int v   = t + 256 * i;         // 0..1023 int4-groups
        int row = v >> 4;              // k within tile
        int cq  = v & 15;              // int4 group within row
        int4 x = *(const int4*)(w + (size_t)(k0 + row) * N_DIM + n0 + cq * 4);
        lds[row][cq * 4 + 0] = x.x;
        lds[row][cq * 4 + 1] = x.y;
        lds[row][cq * 4 + 2] = x.z;
        lds[row][cq * 4 + 3] = x.w;
    }
    __syncthreads();

    const int n_local = t >> 2;        // 0..63
    const int c       = t & 3;         // 16-byte k-chunk
    uint32_t o[4];
#pragma unroll
    for (int j = 0; j < 4; ++j)
        o[j] = pack4(lds[c * 16 + j * 4 + 0][n_local],
                     lds[c * 16 + j * 4 + 1][n_local],
                     lds[c * 16 + j * 4 + 2][n_local],
                     lds[c * 16 + j * 4 + 3][n_local]);
    *(uint4*)(wt + (size_t)(n0 + n_local) * K_DIM + k0 + c * 16) =
        make_uint4(o[0], o[1], o[2], o[3]);
}

// ---------------------------------------------------------------------------
// int8 GEMM — 256x256 tile, 8 waves, BK=128, double-buffered FRAGMENT-ORDER
// LDS.  Each 1 KiB LDS region holds exactly one MFMA operand tile in lane
// order: region(a,s), lane l  <->  A[a*32 + (l&31)][s*32 + (l>>5)*16 ..+15].
// The per-lane *global* source of global_load_lds does the reordering (the
// LDS dest stays linear, base + lane*16, as the HW requires).  Every
// ds_read_b128 is then a wave-contiguous 1024B read: zero bank conflicts,
// minimal 8-cyc port occupancy.  This removes the structural 4-way quad
// conflict of row-major 64B rows (bank index can't see row bits >1).
//
// Schedule = catalog minimum 2-phase (T3): front-load the 8 staging loads of
// tile kt+1, compute 4 k-steps of tile kt, one vmcnt(0)+barrier per K-tile.
// Issue-to-wait distance ~ full tile compute, so the drain costs ~nothing.
// T5 setprio around MFMA clusters.  T1 XCD swizzle: 512 blocks -> 8 XCDs,
// each gets a compact 8bm x 8bn octant.
// ---------------------------------------------------------------------------
__device__ __forceinline__ void async_copy16(const void* gptr, void* lptr)
{
    __builtin_amdgcn_global_load_lds(
        (const __attribute__((address_space(1))) uint32_t*)gptr,
        (__attribute__((address_space(3))) uint32_t*)lptr,
        16, 0, 0);
}

#define VMCNT0() asm volatile("s_waitcnt vmcnt(0)" ::: "memory")

__global__ void __launch_bounds__(512, 2) int8_gemm_kernel(
    const uint8_t* __restrict__ A,    // [M][K] int8 bytes (packed)
    const uint8_t* __restrict__ Wt,   // [N][K] int8 bytes (pre-transposed)
    const float*   __restrict__ a_s,  // [M]
    const float*   __restrict__ w_s,  // [N]
    float*         __restrict__ out)  // [M][N] f32 (fp16-rounded)
{
    // [dbuf][kstep s][subtile a/b][1024B operand region]
    __shared__ __align__(16) uint8_t sA[2][4][8][1024];
    __shared__ __align__(16) uint8_t sB[2][4][8][1024];

    const int tid   = threadIdx.x;
    const int wave  = tid >> 6;       // 0..7
    const int lane  = tid & 63;
    const int waveM = wave >> 2;      // 0..1  -> 128-row M slab
    const int waveN = wave & 3;       // 0..3  -> 64-col N slab

    // XCD-aware swizzle: 512 blocks, xcd = bid&7 owns an 8x8 (bm,bn) octant.
    const int bid = blockIdx.x;
    const int xc  = bid & 7;
    const int j   = bid >> 3;         // 0..63
    const int bm  = (xc & 3) * 8 + (j & 7);    // 0..31
    const int bn  = (xc >> 2) * 8 + (j >> 3);  // 0..15
    const int m0  = bm * 256;
    const int n0  = bn * 256;

    v16i acc[4][2];
#pragma unroll
    for (int i = 0; i < 4; ++i)
#pragma unroll
        for (int jj = 0; jj < 2; ++jj)
#pragma unroll
            for (int r = 0; r < 16; ++r)
                acc[i][jj][r] = 0;

    // Per-thread global source base for fragment-order staging.
    // Wave w stages A-subtile a=w and B-subtile b=w, all 4 k-steps:
    //   lane l sources  X[base_row + w*32 + (l&31)][kt*128 + s*32 + (l>>5)*16].
    const uint8_t* aSrc = A  + (size_t)(m0 + wave * 32 + (lane & 31)) * K_DIM
                             + ((lane >> 5) << 4);
    const uint8_t* bSrc = Wt + (size_t)(n0 + wave * 32 + (lane & 31)) * K_DIM
                             + ((lane >> 5) << 4);

    auto stage_tile = [&](int buf, int kt) {
        const int ko = kt * 128;
#pragma unroll
        for (int s = 0; s < 4; ++s) {
            async_copy16(aSrc + ko + s * 32, &sA[buf][s][wave][0]);
            async_copy16(bSrc + ko + s * 32, &sB[buf][s][wave][0]);
        }
    };

    // One k-step (32 bytes of K): 4 A-frags + 2 B-frags -> 8 MFMAs.
    // All ds_reads are wave-contiguous: region base + lane*16.
    auto compute_kstep = [&](int buf, int s) {
        v4i af[4], bf[2];
#pragma unroll
        for (int mt = 0; mt < 4; ++mt)
            af[mt] = *(const v4i*)(&sA[buf][s][waveM * 4 + mt][lane * 16]);
#pragma unroll
        for (int nt = 0; nt < 2; ++nt)
            bf[nt] = *(const v4i*)(&sB[buf][s][waveN * 2 + nt][lane * 16]);
        __builtin_amdgcn_s_setprio(1);
#pragma unroll
        for (int mt = 0; mt < 4; ++mt)
#pragma unroll
            for (int nt = 0; nt < 2; ++nt)
                acc[mt][nt] = __builtin_amdgcn_mfma_i32_32x32x32_i8(
                    af[mt], bf[nt], acc[mt][nt], 0, 0, 0);
        __builtin_amdgcn_s_setprio(0);
    };

    const int NT = K_DIM / 128;       // 32 K-tiles

    // ---- prologue: stage tile 0 into buf 0.
    stage_tile(0, 0);
    VMCNT0();
    __builtin_amdgcn_s_barrier();

    // ---- main loop: stage kt+1 (front-loaded), compute kt, wait+barrier.
    for (int kt = 0; kt < NT - 1; ++kt) {
        const int b = kt & 1;
        stage_tile(b ^ 1, kt + 1);
#pragma unroll
        for (int s = 0; s < 4; ++s)
            compute_kstep(b, s);
        VMCNT0();                      // loads issued ~full tile ago: no stall
        __builtin_amdgcn_s_barrier();
    }
    // ---- last tile (buf 1): no staging, no barrier needed after.
#pragma unroll
    for (int s = 0; s < 4; ++s)
        compute_kstep((NT - 1) & 1, s);

    // ---- epilogue. 32x32 C/D layout: col = lane&31,
    // row = (reg&3) + 8*(reg>>2) + 4*(lane>>5).
    const int col   = lane & 31;
    const int rbase = (lane >> 5) * 4;

#pragma unroll
    for (int mt = 0; mt < 4; ++mt) {
        const int mrow0 = m0 + waveM * 128 + mt * 32 + rbase;
        float asv[16];
#pragma unroll
        for (int reg = 0; reg < 16; ++reg)
            asv[reg] = a_s[mrow0 + (reg & 3) + 8 * (reg >> 2)];
#pragma unroll
        for (int nt = 0; nt < 2; ++nt) {
            const int n = n0 + waveN * 64 + nt * 32 + col;
            const float wsv = w_s[n];
#pragma unroll
            for (int reg = 0; reg < 16; ++reg) {
                const int row = mrow0 + (reg & 3) + 8 * (reg >> 2);
                float v = (float)acc[mt][nt][reg] * asv[reg] * wsv;
                v = (float)(_Float16)v;   // match reference's fp16 cast
                out[(size_t)row * N_DIM + n] = v;
            }
        }
    }
}

// ---------------------------------------------------------------------------
extern "C" void kernel_launch(void* const* d_in, const int* in_sizes, int n_in,
                              void* d_out, int out_size, void* d_ws, size_t ws_size,
                              hipStream_t stream)
{
    const int*   a   = (const int*)  d_in[0];  // int32-widened int8 [8192][4096]
    const float* a_s = (const float*)d_in[1];  // [8192]
    const int*   w   = (const int*)  d_in[2];  // int32-widened int8 [4096][4096]
    const float* w_s = (const float*)d_in[3];  // [4096]
    float*       out = (float*)d_out;

    uint8_t* wt = (uint8_t*)d_ws;                          // 16 MiB
    uint8_t* pa = (uint8_t*)d_ws + (size_t)N_DIM * K_DIM;  // 32 MiB

    prepare_kernel<<<PACKA_BLOCKS + TRANS_BLOCKS, 256, 0, stream>>>(a, w, pa, wt);

    int8_gemm_kernel<<<(M_DIM / 256) * (N_DIM / 256), 512, 0, stream>>>(
        pa, wt, a_s, w_s, out);
}

// Round 4
// 406.032 us; speedup vs baseline: 1.1341x; 1.1341x over previous
//
#include <hip/hip_runtime.h>
#include <cstdint>
#include <cstddef>

// Problem: a[B=4,S=2048,K=4096] int8, w[K=4096,N=4096] int8,
// a_s[8192] f32 per-token scale, w_s[4096] f32 per-col scale.
// out[m][n] = fp16( (int32 dot) * a_s[m] * w_s[n] ), stored as f32 in d_out.
//
// Fragment-order DRAM layout (written by prepare_kernel):
//   A_f byte((m,k)) = ((m>>5)*128 + (k>>5))*1024 + ((m&31) + 32*((k>>4)&1))*16 + (k&15)
//   W_f byte((n,k)) = ((n>>5)*128 + (k>>5))*1024 + ((n&31) + 32*((k>>4)&1))*16 + (k&15)
// Each 1 KiB "region" (32-row block, 32B k-step) is one mfma_i32_32x32x32_i8
// operand tile in lane order: lane l <-> row (l&31), k-half (l>>5).
// GEMM staging loads are 64 lanes x 16B CONTIGUOUS (perfect coalescing,
// fixes R3's scattered-source regression) and LDS reads are wave-contiguous
// base + lane*16 (zero bank conflicts, kept from R3).

#define M_DIM 8192
#define N_DIM 4096
#define K_DIM 4096

#define PREP_A_BLOCKS ((M_DIM / 32) * (K_DIM / 128))   // 8192
#define PREP_W_BLOCKS ((N_DIM / 64) * (K_DIM / 64))    // 4096

typedef int v4i  __attribute__((ext_vector_type(4)));
typedef int v16i __attribute__((ext_vector_type(16)));

__device__ __forceinline__ uint32_t pack4(int x, int y, int z, int w)
{
    return (uint32_t)(x & 0xff) | ((uint32_t)(y & 0xff) << 8) |
           ((uint32_t)(z & 0xff) << 16) | ((uint32_t)(w & 0xff) << 24);
}

// ---------------------------------------------------------------------------
// Pre-pass. Blocks [0, PREP_A_BLOCKS): narrow A int32->int8 and write
// fragment-order (32m x 128k patch -> 4 regions = 4KB, via an XOR-swizzled
// LDS image; global loads and stores fully coalesced, LDS <=2-way both
// sides). Remaining blocks: W narrow + transpose + fragment-order via the
// padded 64x64 tile (loads/LDS unchanged from the proven version; new
// chunk-assembling read side + coalesced 16B stores).
// ---------------------------------------------------------------------------
__global__ void __launch_bounds__(256) prepare_kernel(
    const int* __restrict__ a, const int* __restrict__ w,
    uint8_t* __restrict__ a_f, uint8_t* __restrict__ w_f)
{
    __shared__ int lds[64][65];
    const int t = threadIdx.x;

    if (blockIdx.x < PREP_A_BLOCKS) {
        uint32_t* l32 = (uint32_t*)&lds[0][0];   // 4KB image, XOR-swizzled
        const int bm = blockIdx.x >> 5;          // 0..255  (32-row block)
        const int bk = blockIdx.x & 31;          // 0..31   (128-col block)
        const int m0 = bm * 32;
        const int k0 = bk * 128;
#pragma unroll
        for (int i = 0; i < 4; ++i) {
            const int f = i * 256 + t;           // int4-group 0..1023 (coalesced)
            const int r = f >> 5;                // row in patch 0..31
            const int c = (f << 2) & 127;        // int32 col in patch (%4==0)
            int4 x = *(const int4*)(a + (size_t)(m0 + r) * K_DIM + k0 + c);
            uint32_t u = pack4(x.x, x.y, x.z, x.w);
            const int region = c >> 5;                       // 0..3
            const int chunk  = r + (((c >> 4) & 1) << 5);    // 0..63
            const int wd     = region * 256 + chunk * 4 + ((c & 15) >> 2);
            l32[wd ^ ((region & 3) << 3)] = u;
        }
        __syncthreads();
        uint4 o = ((const uint4*)l32)[t ^ (((t >> 6) & 3) << 1)];
        *(uint4*)(a_f + ((size_t)bm * 128 + bk * 4) * 1024 + t * 16) = o;
        return;
    }

    // ---- W branch: 64k x 64n tile -> 4 regions (2 n-blocks x 2 k32).
    const int tile = blockIdx.x - PREP_A_BLOCKS;
    const int n0 = (tile & 63) * 64;
    const int k0 = (tile >> 6) * 64;

#pragma unroll
    for (int i = 0; i < 4; ++i) {
        int v   = t + 256 * i;
        int row = v >> 4;              // k within tile
        int cq  = v & 15;              // int4 group within row
        int4 x = *(const int4*)(w + (size_t)(k0 + row) * N_DIM + n0 + cq * 4);
        lds[row][cq * 4 + 0] = x.x;
        lds[row][cq * 4 + 1] = x.y;
        lds[row][cq * 4 + 2] = x.z;
        lds[row][cq * 4 + 3] = x.w;
    }
    __syncthreads();

    const int chunk  = t & 63;         // output chunk within region
    const int r_out  = t >> 6;         // 0..3
    const int nb     = r_out >> 1;     // n-block within tile (0..1)
    const int kk     = r_out & 1;      // k32 within tile (0..1)
    const int ncol   = nb * 32 + (chunk & 31);
    const int parity = chunk >> 5;
    const int rbase  = kk * 32 + parity * 16;
    uint32_t o[4];
#pragma unroll
    for (int q = 0; q < 4; ++q)
        o[q] = pack4(lds[rbase + q * 4 + 0][ncol],
                     lds[rbase + q * 4 + 1][ncol],
                     lds[rbase + q * 4 + 2][ncol],
                     lds[rbase + q * 4 + 3][ncol]);
    *(uint4*)(w_f + (((size_t)(n0 >> 5) + nb) * 128 + (k0 >> 5) + kk) * 1024
                  + chunk * 16) = make_uint4(o[0], o[1], o[2], o[3]);
}

// ---------------------------------------------------------------------------
// int8 GEMM — 256x256 tile, 8 waves, BK=128, double-buffered fragment-order
// LDS [dbuf][kstep][8 regions][1KiB].  Staging: per (wave,s) one contiguous
// 1KiB global_load_lds for A and one for B.  Reads: base + lane*16, zero
// conflicts.  Schedule: counted-vmcnt 2-barrier interleave (T3+T4): per tile
//   phaseA: stage s0,s1 of kt+1 | compute s0,s1 | vmcnt(4) barrier
//   phaseB: stage s2,s3 of kt+1 | compute s2,s3 | vmcnt(4) barrier
// Each vmcnt(4) retires exactly the 4 loads consumed next; never drained to
// 0 in-loop.  T5 setprio around MFMA clusters; T1 XCD octant swizzle.
// ---------------------------------------------------------------------------
__device__ __forceinline__ void async_copy16(const void* gptr, void* lptr)
{
    __builtin_amdgcn_global_load_lds(
        (const __attribute__((address_space(1))) uint32_t*)gptr,
        (__attribute__((address_space(3))) uint32_t*)lptr,
        16, 0, 0);
}

#define VMCNT4() asm volatile("s_waitcnt vmcnt(4)" ::: "memory")
#define VMCNT0() asm volatile("s_waitcnt vmcnt(0)" ::: "memory")

__global__ void __launch_bounds__(512, 2) int8_gemm_kernel(
    const uint8_t* __restrict__ Af,   // fragment-order A (32 MiB)
    const uint8_t* __restrict__ Wf,   // fragment-order W (16 MiB)
    const float*   __restrict__ a_s,  // [M]
    const float*   __restrict__ w_s,  // [N]
    float*         __restrict__ out)  // [M][N] f32 (fp16-rounded)
{
    __shared__ __align__(16) uint8_t sA[2][4][8][1024];
    __shared__ __align__(16) uint8_t sB[2][4][8][1024];

    const int tid   = threadIdx.x;
    const int wave  = tid >> 6;       // 0..7
    const int lane  = tid & 63;
    const int waveM = wave >> 2;      // 0..1  -> 128-row M slab
    const int waveN = wave & 3;       // 0..3  -> 64-col N slab

    // XCD-aware swizzle: 512 blocks, xcd = bid&7 owns an 8x8 (bm,bn) octant.
    const int bid = blockIdx.x;
    const int xc  = bid & 7;
    const int j   = bid >> 3;
    const int bm  = (xc & 3) * 8 + (j & 7);    // 0..31
    const int bn  = (xc >> 2) * 8 + (j >> 3);  // 0..15
    const int m0  = bm * 256;
    const int n0  = bn * 256;

    v16i acc[4][2];
#pragma unroll
    for (int i = 0; i < 4; ++i)
#pragma unroll
        for (int jj = 0; jj < 2; ++jj)
#pragma unroll
            for (int r = 0; r < 16; ++r)
                acc[i][jj][r] = 0;

    // Per-thread staging bases: wave w stages A-region a=w and B-region b=w.
    const uint8_t* aBase = Af + (((size_t)(m0 >> 5) + wave) * 128) * 1024 + lane * 16;
    const uint8_t* bBase = Wf + (((size_t)(n0 >> 5) + wave) * 128) * 1024 + lane * 16;

    auto stage2 = [&](int buf, int kt, int s0) {   // stage k-steps s0, s0+1
#pragma unroll
        for (int s = s0; s < s0 + 2; ++s) {
            async_copy16(aBase + (size_t)(kt * 4 + s) * 1024, &sA[buf][s][wave][0]);
            async_copy16(bBase + (size_t)(kt * 4 + s) * 1024, &sB[buf][s][wave][0]);
        }
    };

    // One k-step: 4 A-frags + 2 B-frags -> 8 MFMAs; all reads base+lane*16.
    auto compute_kstep = [&](int buf, int s) {
        v4i af[4], bf[2];
#pragma unroll
        for (int mt = 0; mt < 4; ++mt)
            af[mt] = *(const v4i*)(&sA[buf][s][waveM * 4 + mt][lane * 16]);
#pragma unroll
        for (int nt = 0; nt < 2; ++nt)
            bf[nt] = *(const v4i*)(&sB[buf][s][waveN * 2 + nt][lane * 16]);
        __builtin_amdgcn_s_setprio(1);
#pragma unroll
        for (int mt = 0; mt < 4; ++mt)
#pragma unroll
            for (int nt = 0; nt < 2; ++nt)
                acc[mt][nt] = __builtin_amdgcn_mfma_i32_32x32x32_i8(
                    af[mt], bf[nt], acc[mt][nt], 0, 0, 0);
        __builtin_amdgcn_s_setprio(0);
    };

    const int NT = K_DIM / 128;       // 32 K-tiles

    // ---- prologue: stage all of tile 0; retire s0,s1 (s2,s3 stay in flight).
    stage2(0, 0, 0);
    stage2(0, 0, 2);
    VMCNT4();
    __builtin_amdgcn_s_barrier();

    // ---- main loop (steady state: 4 loads outstanding at tile entry).
    for (int kt = 0; kt < NT - 1; ++kt) {
        const int b = kt & 1;
        stage2(b ^ 1, kt + 1, 0);      // issue s0,s1 of next tile
        compute_kstep(b, 0);
        compute_kstep(b, 1);
        VMCNT4();                      // retires s2,s3 of tile kt
        __builtin_amdgcn_s_barrier();
        stage2(b ^ 1, kt + 1, 2);      // issue s2,s3 of next tile
        compute_kstep(b, 2);
        compute_kstep(b, 3);
        VMCNT4();                      // retires s0,s1 of tile kt+1
        __builtin_amdgcn_s_barrier();
    }
    // ---- last tile: no staging.
    {
        const int b = (NT - 1) & 1;
        compute_kstep(b, 0);
        compute_kstep(b, 1);
        VMCNT0();                      // retires s2,s3 of last tile
        __builtin_amdgcn_s_barrier();
        compute_kstep(b, 2);
        compute_kstep(b, 3);
    }

    // ---- epilogue. 32x32 C/D layout: col = lane&31,
    // row = (reg&3) + 8*(reg>>2) + 4*(lane>>5).
    const int col   = lane & 31;
    const int rbase = (lane >> 5) * 4;

#pragma unroll
    for (int mt = 0; mt < 4; ++mt) {
        const int mrow0 = m0 + waveM * 128 + mt * 32 + rbase;
        float asv[16];
#pragma unroll
        for (int reg = 0; reg < 16; ++reg)
            asv[reg] = a_s[mrow0 + (reg & 3) + 8 * (reg >> 2)];
#pragma unroll
        for (int nt = 0; nt < 2; ++nt) {
            const int n = n0 + waveN * 64 + nt * 32 + col;
            const float wsv = w_s[n];
#pragma unroll
            for (int reg = 0; reg < 16; ++reg) {
                const int row = mrow0 + (reg & 3) + 8 * (reg >> 2);
                float v = (float)acc[mt][nt][reg] * asv[reg] * wsv;
                v = (float)(_Float16)v;   // match reference's fp16 cast
                out[(size_t)row * N_DIM + n] = v;
            }
        }
    }
}

// ---------------------------------------------------------------------------
extern "C" void kernel_launch(void* const* d_in, const int* in_sizes, int n_in,
                              void* d_out, int out_size, void* d_ws, size_t ws_size,
                              hipStream_t stream)
{
    const int*   a   = (const int*)  d_in[0];  // int32-widened int8 [8192][4096]
    const float* a_s = (const float*)d_in[1];  // [8192]
    const int*   w   = (const int*)  d_in[2];  // int32-widened int8 [4096][4096]
    const float* w_s = (const float*)d_in[3];  // [4096]
    float*       out = (float*)d_out;

    uint8_t* w_f = (uint8_t*)d_ws;                          // 16 MiB
    uint8_t* a_f = (uint8_t*)d_ws + (size_t)N_DIM * K_DIM;  // 32 MiB

    prepare_kernel<<<PREP_A_BLOCKS + PREP_W_BLOCKS, 256, 0, stream>>>(
        a, w, a_f, w_f);

    int8_gemm_kernel<<<(M_DIM / 256) * (N_DIM / 256), 512, 0, stream>>>(
        a_f, w_f, a_s, w_s, out);
}

// Round 5
// 394.402 us; speedup vs baseline: 1.1676x; 1.0295x over previous
//
#include <hip/hip_runtime.h>
#include <cstdint>
#include <cstddef>

// Problem: a[B=4,S=2048,K=4096] int8, w[K=4096,N=4096] int8,
// a_s[8192] f32 per-token scale, w_s[4096] f32 per-col scale.
// out[m][n] = fp16( (int32 dot) * a_s[m] * w_s[n] ), stored as f32 in d_out.
//
// Fragment-order DRAM layout (written by prepare_kernel):
//   A_f byte((m,k)) = ((m>>5)*128 + (k>>5))*1024 + ((m&31) + 32*((k>>4)&1))*16 + (k&15)
//   W_f byte((n,k)) = ((n>>5)*128 + (k>>5))*1024 + ((n&31) + 32*((k>>4)&1))*16 + (k&15)
// Each 1 KiB "region" (32-row block, 32B k-step) is one mfma_i32_32x32x32_i8
// operand tile in lane order: lane l <-> row (l&31), k-half (l>>5).
// GEMM staging loads are 64 lanes x 16B CONTIGUOUS and LDS reads are
// wave-contiguous base + lane*16 (zero bank conflicts — verified R4).

#define M_DIM 8192
#define N_DIM 4096
#define K_DIM 4096

#define PREP_A_BLOCKS ((M_DIM / 32) * (K_DIM / 128))   // 8192
#define PREP_W_BLOCKS ((N_DIM / 64) * (K_DIM / 64))    // 4096

typedef int v4i  __attribute__((ext_vector_type(4)));
typedef int v16i __attribute__((ext_vector_type(16)));

__device__ __forceinline__ uint32_t pack4(int x, int y, int z, int w)
{
    return (uint32_t)(x & 0xff) | ((uint32_t)(y & 0xff) << 8) |
           ((uint32_t)(z & 0xff) << 16) | ((uint32_t)(w & 0xff) << 24);
}

// ---------------------------------------------------------------------------
// Pre-pass — byte-identical to round 4 (attribution: GEMM-only change).
// ---------------------------------------------------------------------------
__global__ void __launch_bounds__(256) prepare_kernel(
    const int* __restrict__ a, const int* __restrict__ w,
    uint8_t* __restrict__ a_f, uint8_t* __restrict__ w_f)
{
    __shared__ int lds[64][65];
    const int t = threadIdx.x;

    if (blockIdx.x < PREP_A_BLOCKS) {
        uint32_t* l32 = (uint32_t*)&lds[0][0];   // 4KB image, XOR-swizzled
        const int bm = blockIdx.x >> 5;          // 0..255  (32-row block)
        const int bk = blockIdx.x & 31;          // 0..31   (128-col block)
        const int m0 = bm * 32;
        const int k0 = bk * 128;
#pragma unroll
        for (int i = 0; i < 4; ++i) {
            const int f = i * 256 + t;           // int4-group 0..1023 (coalesced)
            const int r = f >> 5;                // row in patch 0..31
            const int c = (f << 2) & 127;        // int32 col in patch (%4==0)
            int4 x = *(const int4*)(a + (size_t)(m0 + r) * K_DIM + k0 + c);
            uint32_t u = pack4(x.x, x.y, x.z, x.w);
            const int region = c >> 5;                       // 0..3
            const int chunk  = r + (((c >> 4) & 1) << 5);    // 0..63
            const int wd     = region * 256 + chunk * 4 + ((c & 15) >> 2);
            l32[wd ^ ((region & 3) << 3)] = u;
        }
        __syncthreads();
        uint4 o = ((const uint4*)l32)[t ^ (((t >> 6) & 3) << 1)];
        *(uint4*)(a_f + ((size_t)bm * 128 + bk * 4) * 1024 + t * 16) = o;
        return;
    }

    // ---- W branch: 64k x 64n tile -> 4 regions (2 n-blocks x 2 k32).
    const int tile = blockIdx.x - PREP_A_BLOCKS;
    const int n0 = (tile & 63) * 64;
    const int k0 = (tile >> 6) * 64;

#pragma unroll
    for (int i = 0; i < 4; ++i) {
        int v   = t + 256 * i;
        int row = v >> 4;              // k within tile
        int cq  = v & 15;              // int4 group within row
        int4 x = *(const int4*)(w + (size_t)(k0 + row) * N_DIM + n0 + cq * 4);
        lds[row][cq * 4 + 0] = x.x;
        lds[row][cq * 4 + 1] = x.y;
        lds[row][cq * 4 + 2] = x.z;
        lds[row][cq * 4 + 3] = x.w;
    }
    __syncthreads();

    const int chunk  = t & 63;         // output chunk within region
    const int r_out  = t >> 6;         // 0..3
    const int nb     = r_out >> 1;     // n-block within tile (0..1)
    const int kk     = r_out & 1;      // k32 within tile (0..1)
    const int ncol   = nb * 32 + (chunk & 31);
    const int parity = chunk >> 5;
    const int rbase  = kk * 32 + parity * 16;
    uint32_t o[4];
#pragma unroll
    for (int q = 0; q < 4; ++q)
        o[q] = pack4(lds[rbase + q * 4 + 0][ncol],
                     lds[rbase + q * 4 + 1][ncol],
                     lds[rbase + q * 4 + 2][ncol],
                     lds[rbase + q * 4 + 3][ncol]);
    *(uint4*)(w_f + (((size_t)(n0 >> 5) + nb) * 128 + (k0 >> 5) + kk) * 1024
                  + chunk * 16) = make_uint4(o[0], o[1], o[2], o[3]);
}

// ---------------------------------------------------------------------------
// int8 GEMM — 256x256 tile, 8 waves, BK=128, double-buffered fragment-order
// LDS.  m201-style per-phase schedule: phase = 1 k-step (4 phases/K-tile),
//   [6 ds_read_b128 + 2 global_load_lds issued]  (pre-barrier: LDS queue
//   [sched_barrier(0)]                            drains during barrier wait)
//   [s_barrier]
//   [s_waitcnt lgkmcnt(0) + sched_barrier(0)]     (rule #18 fence)
//   [setprio(1)  8x mfma_i32_32x32x32_i8  setprio(0)]
//   [s_waitcnt vmcnt(6)]                          (counted: 2 loads/phase x 3
//   [s_barrier]                                    phases in flight; never 0)
// Pair staged at phase p is consumed at phase p+4 and retired by vmcnt(6) at
// end of phase p+3 — issue-to-wait distance = 4 phases (~full HBM latency).
// Last tile peeled with descending vmcnt(4/2/0).  T1 XCD octant swizzle.
// ---------------------------------------------------------------------------
__device__ __forceinline__ void async_copy16(const void* gptr, void* lptr)
{
    __builtin_amdgcn_global_load_lds(
        (const __attribute__((address_space(1))) uint32_t*)gptr,
        (__attribute__((address_space(3))) uint32_t*)lptr,
        16, 0, 0);
}

#define WAIT_VMCNT(n) asm volatile("s_waitcnt vmcnt(" #n ")" ::: "memory")
#define WAIT_LGKM0()  asm volatile("s_waitcnt lgkmcnt(0)" ::: "memory")
#define SCHED_FENCE() __builtin_amdgcn_sched_barrier(0)

__global__ void __launch_bounds__(512, 2) int8_gemm_kernel(
    const uint8_t* __restrict__ Af,   // fragment-order A (32 MiB)
    const uint8_t* __restrict__ Wf,   // fragment-order W (16 MiB)
    const float*   __restrict__ a_s,  // [M]
    const float*   __restrict__ w_s,  // [N]
    float*         __restrict__ out)  // [M][N] f32 (fp16-rounded)
{
    __shared__ __align__(16) uint8_t sA[2][4][8][1024];
    __shared__ __align__(16) uint8_t sB[2][4][8][1024];

    const int tid   = threadIdx.x;
    const int wave  = tid >> 6;       // 0..7
    const int lane  = tid & 63;
    const int waveM = wave >> 2;      // 0..1  -> 128-row M slab
    const int waveN = wave & 3;       // 0..3  -> 64-col N slab

    // XCD-aware swizzle: 512 blocks, xcd = bid&7 owns an 8x8 (bm,bn) octant.
    const int bid = blockIdx.x;
    const int xc  = bid & 7;
    const int j   = bid >> 3;
    const int bm  = (xc & 3) * 8 + (j & 7);    // 0..31
    const int bn  = (xc >> 2) * 8 + (j >> 3);  // 0..15
    const int m0  = bm * 256;
    const int n0  = bn * 256;

    v16i acc[4][2];
#pragma unroll
    for (int i = 0; i < 4; ++i)
#pragma unroll
        for (int jj = 0; jj < 2; ++jj)
#pragma unroll
            for (int r = 0; r < 16; ++r)
                acc[i][jj][r] = 0;

    // Per-thread staging bases: wave w stages A-region a=w and B-region b=w.
    const uint8_t* aBase = Af + (((size_t)(m0 >> 5) + wave) * 128) * 1024 + lane * 16;
    const uint8_t* bBase = Wf + (((size_t)(n0 >> 5) + wave) * 128) * 1024 + lane * 16;

    const int NT = K_DIM / 128;       // 32 K-tiles, 4 k-steps each

    // ---- prologue: stage all 4 pairs of tile 0; retire pair s0; barrier.
#pragma unroll
    for (int s = 0; s < 4; ++s) {
        async_copy16(aBase + (size_t)s * 1024, &sA[0][s][wave][0]);
        async_copy16(bBase + (size_t)s * 1024, &sB[0][s][wave][0]);
    }
    WAIT_VMCNT(6);
    SCHED_FENCE();
    __builtin_amdgcn_s_barrier();

    // ---- main loop.
    for (int kt = 0; kt < NT - 1; ++kt) {
        const int b = kt & 1;
#pragma unroll
        for (int s = 0; s < 4; ++s) {
            v4i af[4], bf[2];
#pragma unroll
            for (int mt = 0; mt < 4; ++mt)
                af[mt] = *(const v4i*)(&sA[b][s][waveM * 4 + mt][lane * 16]);
#pragma unroll
            for (int nt = 0; nt < 2; ++nt)
                bf[nt] = *(const v4i*)(&sB[b][s][waveN * 2 + nt][lane * 16]);
            // stage k-step s of tile kt+1 (consumed 4 phases from now)
            async_copy16(aBase + (size_t)((kt + 1) * 4 + s) * 1024,
                         &sA[b ^ 1][s][wave][0]);
            async_copy16(bBase + (size_t)((kt + 1) * 4 + s) * 1024,
                         &sB[b ^ 1][s][wave][0]);
            SCHED_FENCE();                       // pin reads+stage above barrier
            __builtin_amdgcn_s_barrier();
            WAIT_LGKM0();
            SCHED_FENCE();                       // rule #18: no MFMA hoisting
            __builtin_amdgcn_s_setprio(1);
#pragma unroll
            for (int mt = 0; mt < 4; ++mt)
#pragma unroll
                for (int nt = 0; nt < 2; ++nt)
                    acc[mt][nt] = __builtin_amdgcn_mfma_i32_32x32x32_i8(
                        af[mt], bf[nt], acc[mt][nt], 0, 0, 0);
            __builtin_amdgcn_s_setprio(0);
            WAIT_VMCNT(6);                       // retires pair issued 4 phases ago
            SCHED_FENCE();
            __builtin_amdgcn_s_barrier();
        }
    }

    // ---- last tile (no staging): descending counted vmcnt 4/2/0.
    {
        const int b = (NT - 1) & 1;
#pragma unroll
        for (int s = 0; s < 4; ++s) {
            v4i af[4], bf[2];
#pragma unroll
            for (int mt = 0; mt < 4; ++mt)
                af[mt] = *(const v4i*)(&sA[b][s][waveM * 4 + mt][lane * 16]);
#pragma unroll
            for (int nt = 0; nt < 2; ++nt)
                bf[nt] = *(const v4i*)(&sB[b][s][waveN * 2 + nt][lane * 16]);
            SCHED_FENCE();
            __builtin_amdgcn_s_barrier();
            WAIT_LGKM0();
            SCHED_FENCE();
            __builtin_amdgcn_s_setprio(1);
#pragma unroll
            for (int mt = 0; mt < 4; ++mt)
#pragma unroll
                for (int nt = 0; nt < 2; ++nt)
                    acc[mt][nt] = __builtin_amdgcn_mfma_i32_32x32x32_i8(
                        af[mt], bf[nt], acc[mt][nt], 0, 0, 0);
            __builtin_amdgcn_s_setprio(0);
            if (s == 0) { WAIT_VMCNT(4); }       // retire pair s1
            else if (s == 1) { WAIT_VMCNT(2); }  // retire pair s2
            else if (s == 2) { WAIT_VMCNT(0); }  // retire pair s3
            SCHED_FENCE();
            if (s < 3) __builtin_amdgcn_s_barrier();
        }
    }

    // ---- epilogue. 32x32 C/D layout: col = lane&31,
    // row = (reg&3) + 8*(reg>>2) + 4*(lane>>5).
    const int col   = lane & 31;
    const int rbase = (lane >> 5) * 4;

#pragma unroll
    for (int mt = 0; mt < 4; ++mt) {
        const int mrow0 = m0 + waveM * 128 + mt * 32 + rbase;
        float asv[16];
#pragma unroll
        for (int reg = 0; reg < 16; ++reg)
            asv[reg] = a_s[mrow0 + (reg & 3) + 8 * (reg >> 2)];
#pragma unroll
        for (int nt = 0; nt < 2; ++nt) {
            const int n = n0 + waveN * 64 + nt * 32 + col;
            const float wsv = w_s[n];
#pragma unroll
            for (int reg = 0; reg < 16; ++reg) {
                const int row = mrow0 + (reg & 3) + 8 * (reg >> 2);
                float v = (float)acc[mt][nt][reg] * asv[reg] * wsv;
                v = (float)(_Float16)v;   // match reference's fp16 cast
                out[(size_t)row * N_DIM + n] = v;
            }
        }
    }
}

// ---------------------------------------------------------------------------
extern "C" void kernel_launch(void* const* d_in, const int* in_sizes, int n_in,
                              void* d_out, int out_size, void* d_ws, size_t ws_size,
                              hipStream_t stream)
{
    const int*   a   = (const int*)  d_in[0];  // int32-widened int8 [8192][4096]
    const float* a_s = (const float*)d_in[1];  // [8192]
    const int*   w   = (const int*)  d_in[2];  // int32-widened int8 [4096][4096]
    const float* w_s = (const float*)d_in[3];  // [4096]
    float*       out = (float*)d_out;

    uint8_t* w_f = (uint8_t*)d_ws;                          // 16 MiB
    uint8_t* a_f = (uint8_t*)d_ws + (size_t)N_DIM * K_DIM;  // 32 MiB

    prepare_kernel<<<PREP_A_BLOCKS + PREP_W_BLOCKS, 256, 0, stream>>>(
        a, w, a_f, w_f);

    int8_gemm_kernel<<<(M_DIM / 256) * (N_DIM / 256), 512, 0, stream>>>(
        a_f, w_f, a_s, w_s, out);
}